// Round 6
// baseline (198.465 us; speedup 1.0000x reference)
//
#include <hip/hip_runtime.h>

// UV_Aggregator fused, race-hardened: one wave per b (grid 4096 x 64),
// MFMA f16 16x16x32. Single 8KB LDS tile T with STRICT phase separation:
// every read phase pulls T into registers, then __syncthreads, then the next
// write phase. No inline-asm waitcnts, no in-flight in-place overwrites.
// Weights are loaded as fp32 directly from inputs (no workspace use).

#define LNB 50

typedef _Float16 f16x8 __attribute__((ext_vector_type(8)));
typedef float    f32x4 __attribute__((ext_vector_type(4)));

// byte offset into a [64][64] f16 tile (128 B rows), XOR swizzle (T2-style)
__device__ __forceinline__ int swz(int r, int bytecol) {
  return (r * 128 + bytecol) ^ ((r & 7) << 4);
}

// load 8 consecutive fp32, round-to-nearest-even to f16 (matches (_Float16)x)
__device__ __forceinline__ f16x8 cvt8(const float* __restrict__ p) {
  const float4 lo = *(const float4*)p;
  const float4 hi = *(const float4*)(p + 4);
  f16x8 a;
  a[0] = (_Float16)lo.x; a[1] = (_Float16)lo.y;
  a[2] = (_Float16)lo.z; a[3] = (_Float16)lo.w;
  a[4] = (_Float16)hi.x; a[5] = (_Float16)hi.y;
  a[6] = (_Float16)hi.z; a[7] = (_Float16)hi.w;
  return a;
}

__global__ __launch_bounds__(64, 4) void uvagg_fused(
    const int* __restrict__ nodes,
    const int* __restrict__ hist_uv,
    const int* __restrict__ hist_r,
    const float* __restrict__ v2e,
    const float* __restrict__ u2e,
    const float* __restrict__ r2e,
    const float* __restrict__ w1,
    const float* __restrict__ b1,
    const float* __restrict__ w2,
    const float* __restrict__ b2,
    const float* __restrict__ a1,
    const float* __restrict__ ab1,
    const float* __restrict__ a2,
    const float* __restrict__ ab2,
    const float* __restrict__ a3w,
    float* __restrict__ out) {
  __shared__ _Float16 T[64 * 64];   // 8 KB: H -> O -> P, phase-separated
  __shared__ float scb[64];
  __shared__ float wtb[64];
  const int lane = threadIdx.x;
  const int lr = lane & 15;
  const int kq = lane >> 4;
  const int b = blockIdx.x;

  // ---- Phase 1: H = relu([e_uv;e_r] @ W1^T + b1)  [T: WRITE] -------------
  {
    f16x8 Bf[4][4];
#pragma unroll
    for (int kt = 0; kt < 4; ++kt)
#pragma unroll
      for (int nt = 0; nt < 4; ++nt)
        Bf[kt][nt] = cvt8(w1 + (nt * 16 + lr) * 128 + kt * 32 + kq * 8);

    float bias1[4];
#pragma unroll
    for (int nt = 0; nt < 4; ++nt) bias1[nt] = b1[nt * 16 + lr];

#pragma unroll
    for (int m = 0; m < 4; ++m) {
      // pad rows (50..63) clamp to row 49: finite garbage, masked later
      const int rr = b * LNB + (m * 16 + lr < LNB ? m * 16 + lr : LNB - 1);
      const int iu = hist_uv[rr];
      const int ir = hist_r[rr];
      const float* pu = v2e + (size_t)iu * 64;
      const float* pr = r2e + (size_t)ir * 64;   // R=5 -> cache-resident
      f16x8 A[4];
      A[0] = cvt8(pu + kq * 8);
      A[1] = cvt8(pu + 32 + kq * 8);
      A[2] = cvt8(pr + kq * 8);
      A[3] = cvt8(pr + 32 + kq * 8);
#pragma unroll
      for (int nt = 0; nt < 4; ++nt) {
        f32x4 acc = {0.f, 0.f, 0.f, 0.f};
#pragma unroll
        for (int kt = 0; kt < 4; ++kt)
          acc = __builtin_amdgcn_mfma_f32_16x16x32_f16(A[kt], Bf[kt][nt], acc, 0, 0, 0);
        const int c = nt * 16 + lr;
#pragma unroll
        for (int j = 0; j < 4; ++j) {
          const int row = m * 16 + kq * 4 + j;
          const float v = fmaxf(acc[j] + bias1[nt], 0.f);
          *(_Float16*)((char*)T + swz(row, 2 * c)) = (_Float16)v;
        }
      }
    }
  }
  __syncthreads();

  // ---- Phase 2: H A-fragments -> registers  [T: READ] --------------------
  f16x8 HA0[4], HA1[4];
#pragma unroll
  for (int m = 0; m < 4; ++m) {
    const int r = m * 16 + lr;
    HA0[m] = *(const f16x8*)((char*)T + swz(r, 2 * (kq * 8)));
    HA1[m] = *(const f16x8*)((char*)T + swz(r, 2 * (32 + kq * 8)));
  }
  __syncthreads();

  // ---- Phase 3: O = relu(H @ W2^T + b2) from regs  [T: WRITE] ------------
  {
    f16x8 Bf[2][4];
#pragma unroll
    for (int kt = 0; kt < 2; ++kt)
#pragma unroll
      for (int nt = 0; nt < 4; ++nt)
        Bf[kt][nt] = cvt8(w2 + (nt * 16 + lr) * 64 + kt * 32 + kq * 8);

    float bias2[4];
#pragma unroll
    for (int nt = 0; nt < 4; ++nt) bias2[nt] = b2[nt * 16 + lr];

#pragma unroll
    for (int m = 0; m < 4; ++m) {
#pragma unroll
      for (int nt = 0; nt < 4; ++nt) {
        f32x4 acc = {0.f, 0.f, 0.f, 0.f};
        acc = __builtin_amdgcn_mfma_f32_16x16x32_f16(HA0[m], Bf[0][nt], acc, 0, 0, 0);
        acc = __builtin_amdgcn_mfma_f32_16x16x32_f16(HA1[m], Bf[1][nt], acc, 0, 0, 0);
        const int c = nt * 16 + lr;
#pragma unroll
        for (int j = 0; j < 4; ++j) {
          const int row = m * 16 + kq * 4 + j;
          const float v = fmaxf(acc[j] + bias2[nt], 0.f);
          *(_Float16*)((char*)T + swz(row, 2 * c)) = (_Float16)v;
        }
      }
    }
  }
  __syncthreads();

  // ---- Phase 4: O A-fragments -> registers (live to the end)  [T: READ] --
  f16x8 OA0[4], OA1[4];
#pragma unroll
  for (int m = 0; m < 4; ++m) {
    const int r = m * 16 + lr;
    OA0[m] = *(const f16x8*)((char*)T + swz(r, 2 * (kq * 8)));
    OA1[m] = *(const f16x8*)((char*)T + swz(r, 2 * (32 + kq * 8)));
  }
  __syncthreads();

  // ---- Phase 5: P = relu([O ; uv_rep] @ A1^T + ab1)  [T: WRITE] ----------
  {
    const int node = nodes[b];
    // uv_rep contribution is row-constant: compute once per nt as C-init
    f32x4 acc_u[4];
    {
      f16x8 Bu[2][4];
#pragma unroll
      for (int kt = 0; kt < 2; ++kt)
#pragma unroll
        for (int nt = 0; nt < 4; ++nt)
          Bu[kt][nt] = cvt8(a1 + (nt * 16 + lr) * 128 + (kt + 2) * 32 + kq * 8);
      const f16x8 U2 = cvt8(u2e + (size_t)node * 64 + kq * 8);
      const f16x8 U3 = cvt8(u2e + (size_t)node * 64 + 32 + kq * 8);
#pragma unroll
      for (int nt = 0; nt < 4; ++nt) {
        f32x4 acc = {0.f, 0.f, 0.f, 0.f};
        acc = __builtin_amdgcn_mfma_f32_16x16x32_f16(U2, Bu[0][nt], acc, 0, 0, 0);
        acc = __builtin_amdgcn_mfma_f32_16x16x32_f16(U3, Bu[1][nt], acc, 0, 0, 0);
        acc_u[nt] = acc;
      }
    }

    f16x8 Bf[2][4];
#pragma unroll
    for (int kt = 0; kt < 2; ++kt)
#pragma unroll
      for (int nt = 0; nt < 4; ++nt)
        Bf[kt][nt] = cvt8(a1 + (nt * 16 + lr) * 128 + kt * 32 + kq * 8);

    float biasa1[4];
#pragma unroll
    for (int nt = 0; nt < 4; ++nt) biasa1[nt] = ab1[nt * 16 + lr];

#pragma unroll
    for (int m = 0; m < 4; ++m) {
#pragma unroll
      for (int nt = 0; nt < 4; ++nt) {
        f32x4 acc = acc_u[nt];
        acc = __builtin_amdgcn_mfma_f32_16x16x32_f16(OA0[m], Bf[0][nt], acc, 0, 0, 0);
        acc = __builtin_amdgcn_mfma_f32_16x16x32_f16(OA1[m], Bf[1][nt], acc, 0, 0, 0);
        const int c = nt * 16 + lr;
#pragma unroll
        for (int j = 0; j < 4; ++j) {
          const int row = m * 16 + kq * 4 + j;
          const float v = fmaxf(acc[j] + biasa1[nt], 0.f);
          *(_Float16*)((char*)T + swz(row, 2 * c)) = (_Float16)v;
        }
      }
    }
  }
  __syncthreads();

  // ---- Phase 6: s = relu(P @ A2^T + ab2) . a3  [T: READ only] ------------
  {
    f16x8 Bf[2][4];
#pragma unroll
    for (int kt = 0; kt < 2; ++kt)
#pragma unroll
      for (int nt = 0; nt < 4; ++nt)
        Bf[kt][nt] = cvt8(a2 + (nt * 16 + lr) * 64 + kt * 32 + kq * 8);

    float biasa2[4], a3c[4];
#pragma unroll
    for (int nt = 0; nt < 4; ++nt) {
      biasa2[nt] = ab2[nt * 16 + lr];
      a3c[nt] = a3w[nt * 16 + lr];
    }

#pragma unroll
    for (int m = 0; m < 4; ++m) {
      const int r = m * 16 + lr;
      f16x8 A0  = *(const f16x8*)((char*)T + swz(r, 2 * (kq * 8)));
      f16x8 A1v = *(const f16x8*)((char*)T + swz(r, 2 * (32 + kq * 8)));
      float part[4] = {0.f, 0.f, 0.f, 0.f};
#pragma unroll
      for (int nt = 0; nt < 4; ++nt) {
        f32x4 acc = {0.f, 0.f, 0.f, 0.f};
        acc = __builtin_amdgcn_mfma_f32_16x16x32_f16(A0,  Bf[0][nt], acc, 0, 0, 0);
        acc = __builtin_amdgcn_mfma_f32_16x16x32_f16(A1v, Bf[1][nt], acc, 0, 0, 0);
#pragma unroll
        for (int j = 0; j < 4; ++j) {
          const float v = fmaxf(acc[j] + biasa2[nt], 0.f);
          part[j] += v * a3c[nt];
        }
      }
#pragma unroll
      for (int mask = 1; mask < 16; mask <<= 1)
#pragma unroll
        for (int j = 0; j < 4; ++j) part[j] += __shfl_xor(part[j], mask);
      if (lr == 0) {
#pragma unroll
        for (int j = 0; j < 4; ++j) scb[m * 16 + kq * 4 + j] = part[j];
      }
    }
  }
  __syncthreads();

  // ---- Phase 7: softmax over neighbors (att3_b shift-invariant) ----------
  {
    float sv = (lane < LNB) ? scb[lane] : -1e30f;
    float mx = sv;
#pragma unroll
    for (int mask = 1; mask < 64; mask <<= 1) mx = fmaxf(mx, __shfl_xor(mx, mask));
    const float e = __expf(sv - mx);
    float s = e;
#pragma unroll
    for (int mask = 1; mask < 64; mask <<= 1) s += __shfl_xor(s, mask);
    wtb[lane] = (lane < LNB) ? (e / s) : 0.f;
  }
  __syncthreads();

  // ---- Phase 8: weighted sum from O register fragments -------------------
  {
    float wrow[4];
#pragma unroll
    for (int m = 0; m < 4; ++m) wrow[m] = wtb[m * 16 + lr];

    float p0[8] = {0,0,0,0,0,0,0,0};
    float p1[8] = {0,0,0,0,0,0,0,0};
#pragma unroll
    for (int m = 0; m < 4; ++m)
#pragma unroll
      for (int i = 0; i < 8; ++i) {
        p0[i] += wrow[m] * (float)OA0[m][i];
        p1[i] += wrow[m] * (float)OA1[m][i];
      }
    // reduce over the 16 rows (lr) within each kq group
#pragma unroll
    for (int mask = 1; mask < 16; mask <<= 1)
#pragma unroll
      for (int i = 0; i < 8; ++i) {
        p0[i] += __shfl_xor(p0[i], mask);
        p1[i] += __shfl_xor(p1[i], mask);
      }
    if (lr == 0) {
#pragma unroll
      for (int i = 0; i < 8; ++i) {
        scb[kq * 8 + i] = p0[i];
        scb[32 + kq * 8 + i] = p1[i];
      }
    }
  }
  __syncthreads();
  out[(size_t)b * 64 + lane] = scb[lane];
}

extern "C" void kernel_launch(void* const* d_in, const int* in_sizes, int n_in,
                              void* d_out, int out_size, void* d_ws, size_t ws_size,
                              hipStream_t stream) {
  (void)in_sizes; (void)n_in; (void)out_size; (void)d_ws; (void)ws_size;
  const int* nodes = (const int*)d_in[0];
  const int* huv   = (const int*)d_in[1];
  const int* hr    = (const int*)d_in[2];
  // d_in[3] history_uvt: unused by reference
  const float* v2e = (const float*)d_in[4];
  const float* u2e = (const float*)d_in[5];
  const float* r2e = (const float*)d_in[6];
  const float* w1  = (const float*)d_in[7];
  const float* b1  = (const float*)d_in[8];
  const float* w2  = (const float*)d_in[9];
  const float* b2  = (const float*)d_in[10];
  const float* a1  = (const float*)d_in[11];
  const float* ab1 = (const float*)d_in[12];
  const float* a2  = (const float*)d_in[13];
  const float* ab2 = (const float*)d_in[14];
  const float* a3  = (const float*)d_in[15];
  // d_in[16] att3_b: constant shift inside softmax -> no effect on output

  uvagg_fused<<<4096, 64, 0, stream>>>(nodes, huv, hr, v2e, u2e, r2e,
                                       w1, b1, w2, b2, a1, ab1, a2, ab2, a3,
                                       (float*)d_out);
}

// Round 10
// 176.136 us; speedup vs baseline: 1.1268x; 1.1268x over previous
//
#include <hip/hip_runtime.h>

// UV_Aggregator fused, race-hardened: one wave per b (grid 4096 x 64),
// MFMA f16 16x16x32. Single 8KB LDS tile T with STRICT phase separation
// (every read phase pulls T into registers, then __syncthreads, then the
// next write phase; no inline-asm waitcnts). Weights pre-converted to f16
// in d_ws by prep_weights (one dwordx4 per B-fragment instead of two fp32
// loads + 8 cvts -- reverses the R6 latency regression).

#define LNB 50

typedef _Float16 f16x8 __attribute__((ext_vector_type(8)));
typedef float    f32x4 __attribute__((ext_vector_type(4)));

// byte offset into a [64][64] f16 tile (128 B rows), XOR swizzle (T2-style)
__device__ __forceinline__ int swz(int r, int bytecol) {
  return (r * 128 + bytecol) ^ ((r & 7) << 4);
}

// load 8 consecutive fp32, round-to-nearest-even to f16
__device__ __forceinline__ f16x8 cvt8(const float* __restrict__ p) {
  const float4 lo = *(const float4*)p;
  const float4 hi = *(const float4*)(p + 4);
  f16x8 a;
  a[0] = (_Float16)lo.x; a[1] = (_Float16)lo.y;
  a[2] = (_Float16)lo.z; a[3] = (_Float16)lo.w;
  a[4] = (_Float16)hi.x; a[5] = (_Float16)hi.y;
  a[6] = (_Float16)hi.z; a[7] = (_Float16)hi.w;
  return a;
}

// fp32 weights -> f16 in workspace (re-run every call; ws re-poisoned each time)
__global__ void prep_weights(const float* __restrict__ w1, const float* __restrict__ w2,
                             const float* __restrict__ a1, const float* __restrict__ a2,
                             _Float16* __restrict__ wf) {
  int i = blockIdx.x * 256 + threadIdx.x;
  if (i < 8192) wf[i]         = (_Float16)w1[i];   // w_r1_w (64x128)
  if (i < 4096) wf[8192 + i]  = (_Float16)w2[i];   // w_r2_w (64x64)
  if (i < 8192) wf[12288 + i] = (_Float16)a1[i];   // att1_w (64x128)
  if (i < 4096) wf[20480 + i] = (_Float16)a2[i];   // att2_w (64x64)
}

__global__ __launch_bounds__(64, 4) void uvagg_fused(
    const int* __restrict__ nodes,
    const int* __restrict__ hist_uv,
    const int* __restrict__ hist_r,
    const float* __restrict__ v2e,
    const float* __restrict__ u2e,
    const float* __restrict__ r2e,
    const float* __restrict__ b1,
    const float* __restrict__ b2,
    const float* __restrict__ ab1,
    const float* __restrict__ ab2,
    const float* __restrict__ a3w,
    const _Float16* __restrict__ wf,
    float* __restrict__ out) {
  __shared__ _Float16 T[64 * 64];   // 8 KB: H -> O -> P, phase-separated
  __shared__ float scb[64];
  __shared__ float wtb[64];
  const int lane = threadIdx.x;
  const int lr = lane & 15;
  const int kq = lane >> 4;
  const int b = blockIdx.x;

  const _Float16* w1f = wf;
  const _Float16* w2f = wf + 8192;
  const _Float16* a1f = wf + 12288;
  const _Float16* a2f = wf + 20480;

  // ---- Phase 1: H = relu([e_uv;e_r] @ W1^T + b1)  [T: WRITE] -------------
  {
    f16x8 Bf[4][4];
#pragma unroll
    for (int kt = 0; kt < 4; ++kt)
#pragma unroll
      for (int nt = 0; nt < 4; ++nt)
        Bf[kt][nt] = *(const f16x8*)(w1f + (nt * 16 + lr) * 128 + kt * 32 + kq * 8);

    float bias1[4];
#pragma unroll
    for (int nt = 0; nt < 4; ++nt) bias1[nt] = b1[nt * 16 + lr];

#pragma unroll
    for (int m = 0; m < 4; ++m) {
      // pad rows (50..63) clamp to row 49: finite garbage, masked later
      const int rr = b * LNB + (m * 16 + lr < LNB ? m * 16 + lr : LNB - 1);
      const int iu = hist_uv[rr];
      const int ir = hist_r[rr];
      const float* pu = v2e + (size_t)iu * 64;
      const float* pr = r2e + (size_t)ir * 64;   // R=5 -> cache-resident
      f16x8 A[4];
      A[0] = cvt8(pu + kq * 8);
      A[1] = cvt8(pu + 32 + kq * 8);
      A[2] = cvt8(pr + kq * 8);
      A[3] = cvt8(pr + 32 + kq * 8);
#pragma unroll
      for (int nt = 0; nt < 4; ++nt) {
        f32x4 acc = {0.f, 0.f, 0.f, 0.f};
#pragma unroll
        for (int kt = 0; kt < 4; ++kt)
          acc = __builtin_amdgcn_mfma_f32_16x16x32_f16(A[kt], Bf[kt][nt], acc, 0, 0, 0);
        const int c = nt * 16 + lr;
#pragma unroll
        for (int j = 0; j < 4; ++j) {
          const int row = m * 16 + kq * 4 + j;
          const float v = fmaxf(acc[j] + bias1[nt], 0.f);
          *(_Float16*)((char*)T + swz(row, 2 * c)) = (_Float16)v;
        }
      }
    }
  }
  __syncthreads();

  // ---- Phase 2: H A-fragments -> registers  [T: READ] --------------------
  f16x8 HA0[4], HA1[4];
#pragma unroll
  for (int m = 0; m < 4; ++m) {
    const int r = m * 16 + lr;
    HA0[m] = *(const f16x8*)((char*)T + swz(r, 2 * (kq * 8)));
    HA1[m] = *(const f16x8*)((char*)T + swz(r, 2 * (32 + kq * 8)));
  }
  __syncthreads();

  // ---- Phase 3: O = relu(H @ W2^T + b2) from regs  [T: WRITE] ------------
  {
    f16x8 Bf[2][4];
#pragma unroll
    for (int kt = 0; kt < 2; ++kt)
#pragma unroll
      for (int nt = 0; nt < 4; ++nt)
        Bf[kt][nt] = *(const f16x8*)(w2f + (nt * 16 + lr) * 64 + kt * 32 + kq * 8);

    float bias2[4];
#pragma unroll
    for (int nt = 0; nt < 4; ++nt) bias2[nt] = b2[nt * 16 + lr];

#pragma unroll
    for (int m = 0; m < 4; ++m) {
#pragma unroll
      for (int nt = 0; nt < 4; ++nt) {
        f32x4 acc = {0.f, 0.f, 0.f, 0.f};
        acc = __builtin_amdgcn_mfma_f32_16x16x32_f16(HA0[m], Bf[0][nt], acc, 0, 0, 0);
        acc = __builtin_amdgcn_mfma_f32_16x16x32_f16(HA1[m], Bf[1][nt], acc, 0, 0, 0);
        const int c = nt * 16 + lr;
#pragma unroll
        for (int j = 0; j < 4; ++j) {
          const int row = m * 16 + kq * 4 + j;
          const float v = fmaxf(acc[j] + bias2[nt], 0.f);
          *(_Float16*)((char*)T + swz(row, 2 * c)) = (_Float16)v;
        }
      }
    }
  }
  __syncthreads();

  // ---- Phase 4: O A-fragments -> registers (live to the end)  [T: READ] --
  f16x8 OA0[4], OA1[4];
#pragma unroll
  for (int m = 0; m < 4; ++m) {
    const int r = m * 16 + lr;
    OA0[m] = *(const f16x8*)((char*)T + swz(r, 2 * (kq * 8)));
    OA1[m] = *(const f16x8*)((char*)T + swz(r, 2 * (32 + kq * 8)));
  }
  __syncthreads();

  // ---- Phase 5: P = relu([O ; uv_rep] @ A1^T + ab1)  [T: WRITE] ----------
  {
    const int node = nodes[b];
    // uv_rep contribution is row-constant: compute once per nt as C-init
    f32x4 acc_u[4];
    {
      f16x8 Bu[2][4];
#pragma unroll
      for (int kt = 0; kt < 2; ++kt)
#pragma unroll
        for (int nt = 0; nt < 4; ++nt)
          Bu[kt][nt] = *(const f16x8*)(a1f + (nt * 16 + lr) * 128 + (kt + 2) * 32 + kq * 8);
      const f16x8 U2 = cvt8(u2e + (size_t)node * 64 + kq * 8);
      const f16x8 U3 = cvt8(u2e + (size_t)node * 64 + 32 + kq * 8);
#pragma unroll
      for (int nt = 0; nt < 4; ++nt) {
        f32x4 acc = {0.f, 0.f, 0.f, 0.f};
        acc = __builtin_amdgcn_mfma_f32_16x16x32_f16(U2, Bu[0][nt], acc, 0, 0, 0);
        acc = __builtin_amdgcn_mfma_f32_16x16x32_f16(U3, Bu[1][nt], acc, 0, 0, 0);
        acc_u[nt] = acc;
      }
    }

    f16x8 Bf[2][4];
#pragma unroll
    for (int kt = 0; kt < 2; ++kt)
#pragma unroll
      for (int nt = 0; nt < 4; ++nt)
        Bf[kt][nt] = *(const f16x8*)(a1f + (nt * 16 + lr) * 128 + kt * 32 + kq * 8);

    float biasa1[4];
#pragma unroll
    for (int nt = 0; nt < 4; ++nt) biasa1[nt] = ab1[nt * 16 + lr];

#pragma unroll
    for (int m = 0; m < 4; ++m) {
#pragma unroll
      for (int nt = 0; nt < 4; ++nt) {
        f32x4 acc = acc_u[nt];
        acc = __builtin_amdgcn_mfma_f32_16x16x32_f16(OA0[m], Bf[0][nt], acc, 0, 0, 0);
        acc = __builtin_amdgcn_mfma_f32_16x16x32_f16(OA1[m], Bf[1][nt], acc, 0, 0, 0);
        const int c = nt * 16 + lr;
#pragma unroll
        for (int j = 0; j < 4; ++j) {
          const int row = m * 16 + kq * 4 + j;
          const float v = fmaxf(acc[j] + biasa1[nt], 0.f);
          *(_Float16*)((char*)T + swz(row, 2 * c)) = (_Float16)v;
        }
      }
    }
  }
  __syncthreads();

  // ---- Phase 6: s = relu(P @ A2^T + ab2) . a3  [T: READ only] ------------
  {
    f16x8 Bf[2][4];
#pragma unroll
    for (int kt = 0; kt < 2; ++kt)
#pragma unroll
      for (int nt = 0; nt < 4; ++nt)
        Bf[kt][nt] = *(const f16x8*)(a2f + (nt * 16 + lr) * 64 + kt * 32 + kq * 8);

    float biasa2[4], a3c[4];
#pragma unroll
    for (int nt = 0; nt < 4; ++nt) {
      biasa2[nt] = ab2[nt * 16 + lr];
      a3c[nt] = a3w[nt * 16 + lr];
    }

#pragma unroll
    for (int m = 0; m < 4; ++m) {
      const int r = m * 16 + lr;
      f16x8 A0  = *(const f16x8*)((char*)T + swz(r, 2 * (kq * 8)));
      f16x8 A1v = *(const f16x8*)((char*)T + swz(r, 2 * (32 + kq * 8)));
      float part[4] = {0.f, 0.f, 0.f, 0.f};
#pragma unroll
      for (int nt = 0; nt < 4; ++nt) {
        f32x4 acc = {0.f, 0.f, 0.f, 0.f};
        acc = __builtin_amdgcn_mfma_f32_16x16x32_f16(A0,  Bf[0][nt], acc, 0, 0, 0);
        acc = __builtin_amdgcn_mfma_f32_16x16x32_f16(A1v, Bf[1][nt], acc, 0, 0, 0);
#pragma unroll
        for (int j = 0; j < 4; ++j) {
          const float v = fmaxf(acc[j] + biasa2[nt], 0.f);
          part[j] += v * a3c[nt];
        }
      }
#pragma unroll
      for (int mask = 1; mask < 16; mask <<= 1)
#pragma unroll
        for (int j = 0; j < 4; ++j) part[j] += __shfl_xor(part[j], mask);
      if (lr == 0) {
#pragma unroll
        for (int j = 0; j < 4; ++j) scb[m * 16 + kq * 4 + j] = part[j];
      }
    }
  }
  __syncthreads();

  // ---- Phase 7: softmax over neighbors (att3_b shift-invariant) ----------
  {
    float sv = (lane < LNB) ? scb[lane] : -1e30f;
    float mx = sv;
#pragma unroll
    for (int mask = 1; mask < 64; mask <<= 1) mx = fmaxf(mx, __shfl_xor(mx, mask));
    const float e = __expf(sv - mx);
    float s = e;
#pragma unroll
    for (int mask = 1; mask < 64; mask <<= 1) s += __shfl_xor(s, mask);
    wtb[lane] = (lane < LNB) ? (e / s) : 0.f;
  }
  __syncthreads();

  // ---- Phase 8: weighted sum from O register fragments -------------------
  {
    float wrow[4];
#pragma unroll
    for (int m = 0; m < 4; ++m) wrow[m] = wtb[m * 16 + lr];

    float p0[8] = {0,0,0,0,0,0,0,0};
    float p1[8] = {0,0,0,0,0,0,0,0};
#pragma unroll
    for (int m = 0; m < 4; ++m)
#pragma unroll
      for (int i = 0; i < 8; ++i) {
        p0[i] += wrow[m] * (float)OA0[m][i];
        p1[i] += wrow[m] * (float)OA1[m][i];
      }
    // reduce over the 16 rows (lr) within each kq group
#pragma unroll
    for (int mask = 1; mask < 16; mask <<= 1)
#pragma unroll
      for (int i = 0; i < 8; ++i) {
        p0[i] += __shfl_xor(p0[i], mask);
        p1[i] += __shfl_xor(p1[i], mask);
      }
    if (lr == 0) {
#pragma unroll
      for (int i = 0; i < 8; ++i) {
        scb[kq * 8 + i] = p0[i];
        scb[32 + kq * 8 + i] = p1[i];
      }
    }
  }
  __syncthreads();
  out[(size_t)b * 64 + lane] = scb[lane];
}

extern "C" void kernel_launch(void* const* d_in, const int* in_sizes, int n_in,
                              void* d_out, int out_size, void* d_ws, size_t ws_size,
                              hipStream_t stream) {
  (void)in_sizes; (void)n_in; (void)out_size; (void)ws_size;
  const int* nodes = (const int*)d_in[0];
  const int* huv   = (const int*)d_in[1];
  const int* hr    = (const int*)d_in[2];
  // d_in[3] history_uvt: unused by reference
  const float* v2e = (const float*)d_in[4];
  const float* u2e = (const float*)d_in[5];
  const float* r2e = (const float*)d_in[6];
  const float* w1  = (const float*)d_in[7];
  const float* b1  = (const float*)d_in[8];
  const float* w2  = (const float*)d_in[9];
  const float* b2  = (const float*)d_in[10];
  const float* a1  = (const float*)d_in[11];
  const float* ab1 = (const float*)d_in[12];
  const float* a2  = (const float*)d_in[13];
  const float* ab2 = (const float*)d_in[14];
  const float* a3  = (const float*)d_in[15];
  // d_in[16] att3_b: constant shift inside softmax -> no effect on output

  _Float16* wf = (_Float16*)d_ws;  // 48 KB of f16 weights
  prep_weights<<<32, 256, 0, stream>>>(w1, w2, a1, a2, wf);
  uvagg_fused<<<4096, 64, 0, stream>>>(nodes, huv, hr, v2e, u2e, r2e,
                                       b1, b2, ab1, ab2, a3, wf,
                                       (float*)d_out);
}

// Round 11
// 155.654 us; speedup vs baseline: 1.2750x; 1.1316x over previous
//
#include <hip/hip_runtime.h>

// UV_Aggregator fused, race-hardened: one wave per b (grid 4096 x 64),
// MFMA f16 16x16x32. Single 8KB LDS tile T with STRICT phase separation.
// Weights pre-converted to f16 in d_ws by prep_weights.
// __launch_bounds__(64,2): (64,4) made the allocator squeeze to 64 VGPRs and
// spill ~77MB/dispatch to scratch (R10: WRITE_SIZE 77.8MB vs 1MB of output).

#define LNB 50

typedef _Float16 f16x8 __attribute__((ext_vector_type(8)));
typedef float    f32x4 __attribute__((ext_vector_type(4)));

// byte offset into a [64][64] f16 tile (128 B rows), XOR swizzle (T2-style)
__device__ __forceinline__ int swz(int r, int bytecol) {
  return (r * 128 + bytecol) ^ ((r & 7) << 4);
}

// load 8 consecutive fp32, round-to-nearest-even to f16
__device__ __forceinline__ f16x8 cvt8(const float* __restrict__ p) {
  const float4 lo = *(const float4*)p;
  const float4 hi = *(const float4*)(p + 4);
  f16x8 a;
  a[0] = (_Float16)lo.x; a[1] = (_Float16)lo.y;
  a[2] = (_Float16)lo.z; a[3] = (_Float16)lo.w;
  a[4] = (_Float16)hi.x; a[5] = (_Float16)hi.y;
  a[6] = (_Float16)hi.z; a[7] = (_Float16)hi.w;
  return a;
}

// fp32 weights -> f16 in workspace (re-run every call; ws re-poisoned each time)
__global__ void prep_weights(const float* __restrict__ w1, const float* __restrict__ w2,
                             const float* __restrict__ a1, const float* __restrict__ a2,
                             _Float16* __restrict__ wf) {
  int i = blockIdx.x * 256 + threadIdx.x;
  if (i < 8192) wf[i]         = (_Float16)w1[i];   // w_r1_w (64x128)
  if (i < 4096) wf[8192 + i]  = (_Float16)w2[i];   // w_r2_w (64x64)
  if (i < 8192) wf[12288 + i] = (_Float16)a1[i];   // att1_w (64x128)
  if (i < 4096) wf[20480 + i] = (_Float16)a2[i];   // att2_w (64x64)
}

__global__ __launch_bounds__(64, 2) void uvagg_fused(
    const int* __restrict__ nodes,
    const int* __restrict__ hist_uv,
    const int* __restrict__ hist_r,
    const float* __restrict__ v2e,
    const float* __restrict__ u2e,
    const float* __restrict__ r2e,
    const float* __restrict__ b1,
    const float* __restrict__ b2,
    const float* __restrict__ ab1,
    const float* __restrict__ ab2,
    const float* __restrict__ a3w,
    const _Float16* __restrict__ wf,
    float* __restrict__ out) {
  __shared__ _Float16 T[64 * 64];   // 8 KB: H -> O -> P, phase-separated
  __shared__ float scb[64];
  __shared__ float wtb[64];
  const int lane = threadIdx.x;
  const int lr = lane & 15;
  const int kq = lane >> 4;
  const int b = blockIdx.x;

  const _Float16* w1f = wf;
  const _Float16* w2f = wf + 8192;
  const _Float16* a1f = wf + 12288;
  const _Float16* a2f = wf + 20480;

  // ---- Phase 1: H = relu([e_uv;e_r] @ W1^T + b1)  [T: WRITE] -------------
  {
    f16x8 Bf[4][4];
#pragma unroll
    for (int kt = 0; kt < 4; ++kt)
#pragma unroll
      for (int nt = 0; nt < 4; ++nt)
        Bf[kt][nt] = *(const f16x8*)(w1f + (nt * 16 + lr) * 128 + kt * 32 + kq * 8);

    float bias1[4];
#pragma unroll
    for (int nt = 0; nt < 4; ++nt) bias1[nt] = b1[nt * 16 + lr];

#pragma unroll
    for (int m = 0; m < 4; ++m) {
      // pad rows (50..63) clamp to row 49: finite garbage, masked later
      const int rr = b * LNB + (m * 16 + lr < LNB ? m * 16 + lr : LNB - 1);
      const int iu = hist_uv[rr];
      const int ir = hist_r[rr];
      const float* pu = v2e + (size_t)iu * 64;
      const float* pr = r2e + (size_t)ir * 64;   // R=5 -> cache-resident
      f16x8 A[4];
      A[0] = cvt8(pu + kq * 8);
      A[1] = cvt8(pu + 32 + kq * 8);
      A[2] = cvt8(pr + kq * 8);
      A[3] = cvt8(pr + 32 + kq * 8);
#pragma unroll
      for (int nt = 0; nt < 4; ++nt) {
        f32x4 acc = {0.f, 0.f, 0.f, 0.f};
#pragma unroll
        for (int kt = 0; kt < 4; ++kt)
          acc = __builtin_amdgcn_mfma_f32_16x16x32_f16(A[kt], Bf[kt][nt], acc, 0, 0, 0);
        const int c = nt * 16 + lr;
#pragma unroll
        for (int j = 0; j < 4; ++j) {
          const int row = m * 16 + kq * 4 + j;
          const float v = fmaxf(acc[j] + bias1[nt], 0.f);
          *(_Float16*)((char*)T + swz(row, 2 * c)) = (_Float16)v;
        }
      }
    }
  }
  __syncthreads();

  // ---- Phase 2: H A-fragments -> registers  [T: READ] --------------------
  f16x8 HA0[4], HA1[4];
#pragma unroll
  for (int m = 0; m < 4; ++m) {
    const int r = m * 16 + lr;
    HA0[m] = *(const f16x8*)((char*)T + swz(r, 2 * (kq * 8)));
    HA1[m] = *(const f16x8*)((char*)T + swz(r, 2 * (32 + kq * 8)));
  }
  __syncthreads();

  // ---- Phase 3: O = relu(H @ W2^T + b2) from regs  [T: WRITE] ------------
  {
    f16x8 Bf[2][4];
#pragma unroll
    for (int kt = 0; kt < 2; ++kt)
#pragma unroll
      for (int nt = 0; nt < 4; ++nt)
        Bf[kt][nt] = *(const f16x8*)(w2f + (nt * 16 + lr) * 64 + kt * 32 + kq * 8);

    float bias2[4];
#pragma unroll
    for (int nt = 0; nt < 4; ++nt) bias2[nt] = b2[nt * 16 + lr];

#pragma unroll
    for (int m = 0; m < 4; ++m) {
#pragma unroll
      for (int nt = 0; nt < 4; ++nt) {
        f32x4 acc = {0.f, 0.f, 0.f, 0.f};
        acc = __builtin_amdgcn_mfma_f32_16x16x32_f16(HA0[m], Bf[0][nt], acc, 0, 0, 0);
        acc = __builtin_amdgcn_mfma_f32_16x16x32_f16(HA1[m], Bf[1][nt], acc, 0, 0, 0);
        const int c = nt * 16 + lr;
#pragma unroll
        for (int j = 0; j < 4; ++j) {
          const int row = m * 16 + kq * 4 + j;
          const float v = fmaxf(acc[j] + bias2[nt], 0.f);
          *(_Float16*)((char*)T + swz(row, 2 * c)) = (_Float16)v;
        }
      }
    }
  }
  __syncthreads();

  // ---- Phase 4: O A-fragments -> registers (live to the end)  [T: READ] --
  f16x8 OA0[4], OA1[4];
#pragma unroll
  for (int m = 0; m < 4; ++m) {
    const int r = m * 16 + lr;
    OA0[m] = *(const f16x8*)((char*)T + swz(r, 2 * (kq * 8)));
    OA1[m] = *(const f16x8*)((char*)T + swz(r, 2 * (32 + kq * 8)));
  }
  __syncthreads();

  // ---- Phase 5: P = relu([O ; uv_rep] @ A1^T + ab1)  [T: WRITE] ----------
  {
    const int node = nodes[b];
    // uv_rep contribution is row-constant: compute once per nt as C-init
    f32x4 acc_u[4];
    {
      f16x8 Bu[2][4];
#pragma unroll
      for (int kt = 0; kt < 2; ++kt)
#pragma unroll
        for (int nt = 0; nt < 4; ++nt)
          Bu[kt][nt] = *(const f16x8*)(a1f + (nt * 16 + lr) * 128 + (kt + 2) * 32 + kq * 8);
      const f16x8 U2 = cvt8(u2e + (size_t)node * 64 + kq * 8);
      const f16x8 U3 = cvt8(u2e + (size_t)node * 64 + 32 + kq * 8);
#pragma unroll
      for (int nt = 0; nt < 4; ++nt) {
        f32x4 acc = {0.f, 0.f, 0.f, 0.f};
        acc = __builtin_amdgcn_mfma_f32_16x16x32_f16(U2, Bu[0][nt], acc, 0, 0, 0);
        acc = __builtin_amdgcn_mfma_f32_16x16x32_f16(U3, Bu[1][nt], acc, 0, 0, 0);
        acc_u[nt] = acc;
      }
    }

    f16x8 Bf[2][4];
#pragma unroll
    for (int kt = 0; kt < 2; ++kt)
#pragma unroll
      for (int nt = 0; nt < 4; ++nt)
        Bf[kt][nt] = *(const f16x8*)(a1f + (nt * 16 + lr) * 128 + kt * 32 + kq * 8);

    float biasa1[4];
#pragma unroll
    for (int nt = 0; nt < 4; ++nt) biasa1[nt] = ab1[nt * 16 + lr];

#pragma unroll
    for (int m = 0; m < 4; ++m) {
#pragma unroll
      for (int nt = 0; nt < 4; ++nt) {
        f32x4 acc = acc_u[nt];
        acc = __builtin_amdgcn_mfma_f32_16x16x32_f16(OA0[m], Bf[0][nt], acc, 0, 0, 0);
        acc = __builtin_amdgcn_mfma_f32_16x16x32_f16(OA1[m], Bf[1][nt], acc, 0, 0, 0);
        const int c = nt * 16 + lr;
#pragma unroll
        for (int j = 0; j < 4; ++j) {
          const int row = m * 16 + kq * 4 + j;
          const float v = fmaxf(acc[j] + biasa1[nt], 0.f);
          *(_Float16*)((char*)T + swz(row, 2 * c)) = (_Float16)v;
        }
      }
    }
  }
  __syncthreads();

  // ---- Phase 6: s = relu(P @ A2^T + ab2) . a3  [T: READ only] ------------
  {
    f16x8 Bf[2][4];
#pragma unroll
    for (int kt = 0; kt < 2; ++kt)
#pragma unroll
      for (int nt = 0; nt < 4; ++nt)
        Bf[kt][nt] = *(const f16x8*)(a2f + (nt * 16 + lr) * 64 + kt * 32 + kq * 8);

    float biasa2[4], a3c[4];
#pragma unroll
    for (int nt = 0; nt < 4; ++nt) {
      biasa2[nt] = ab2[nt * 16 + lr];
      a3c[nt] = a3w[nt * 16 + lr];
    }

#pragma unroll
    for (int m = 0; m < 4; ++m) {
      const int r = m * 16 + lr;
      f16x8 A0  = *(const f16x8*)((char*)T + swz(r, 2 * (kq * 8)));
      f16x8 A1v = *(const f16x8*)((char*)T + swz(r, 2 * (32 + kq * 8)));
      float part[4] = {0.f, 0.f, 0.f, 0.f};
#pragma unroll
      for (int nt = 0; nt < 4; ++nt) {
        f32x4 acc = {0.f, 0.f, 0.f, 0.f};
        acc = __builtin_amdgcn_mfma_f32_16x16x32_f16(A0,  Bf[0][nt], acc, 0, 0, 0);
        acc = __builtin_amdgcn_mfma_f32_16x16x32_f16(A1v, Bf[1][nt], acc, 0, 0, 0);
#pragma unroll
        for (int j = 0; j < 4; ++j) {
          const float v = fmaxf(acc[j] + biasa2[nt], 0.f);
          part[j] += v * a3c[nt];
        }
      }
#pragma unroll
      for (int mask = 1; mask < 16; mask <<= 1)
#pragma unroll
        for (int j = 0; j < 4; ++j) part[j] += __shfl_xor(part[j], mask);
      if (lr == 0) {
#pragma unroll
        for (int j = 0; j < 4; ++j) scb[m * 16 + kq * 4 + j] = part[j];
      }
    }
  }
  __syncthreads();

  // ---- Phase 7: softmax over neighbors (att3_b shift-invariant) ----------
  {
    float sv = (lane < LNB) ? scb[lane] : -1e30f;
    float mx = sv;
#pragma unroll
    for (int mask = 1; mask < 64; mask <<= 1) mx = fmaxf(mx, __shfl_xor(mx, mask));
    const float e = __expf(sv - mx);
    float s = e;
#pragma unroll
    for (int mask = 1; mask < 64; mask <<= 1) s += __shfl_xor(s, mask);
    wtb[lane] = (lane < LNB) ? (e / s) : 0.f;
  }
  __syncthreads();

  // ---- Phase 8: weighted sum from O register fragments -------------------
  {
    float wrow[4];
#pragma unroll
    for (int m = 0; m < 4; ++m) wrow[m] = wtb[m * 16 + lr];

    float p0[8] = {0,0,0,0,0,0,0,0};
    float p1[8] = {0,0,0,0,0,0,0,0};
#pragma unroll
    for (int m = 0; m < 4; ++m)
#pragma unroll
      for (int i = 0; i < 8; ++i) {
        p0[i] += wrow[m] * (float)OA0[m][i];
        p1[i] += wrow[m] * (float)OA1[m][i];
      }
    // reduce over the 16 rows (lr) within each kq group
#pragma unroll
    for (int mask = 1; mask < 16; mask <<= 1)
#pragma unroll
      for (int i = 0; i < 8; ++i) {
        p0[i] += __shfl_xor(p0[i], mask);
        p1[i] += __shfl_xor(p1[i], mask);
      }
    if (lr == 0) {
#pragma unroll
      for (int i = 0; i < 8; ++i) {
        scb[kq * 8 + i] = p0[i];
        scb[32 + kq * 8 + i] = p1[i];
      }
    }
  }
  __syncthreads();
  out[(size_t)b * 64 + lane] = scb[lane];
}

extern "C" void kernel_launch(void* const* d_in, const int* in_sizes, int n_in,
                              void* d_out, int out_size, void* d_ws, size_t ws_size,
                              hipStream_t stream) {
  (void)in_sizes; (void)n_in; (void)out_size; (void)ws_size;
  const int* nodes = (const int*)d_in[0];
  const int* huv   = (const int*)d_in[1];
  const int* hr    = (const int*)d_in[2];
  // d_in[3] history_uvt: unused by reference
  const float* v2e = (const float*)d_in[4];
  const float* u2e = (const float*)d_in[5];
  const float* r2e = (const float*)d_in[6];
  const float* w1  = (const float*)d_in[7];
  const float* b1  = (const float*)d_in[8];
  const float* w2  = (const float*)d_in[9];
  const float* b2  = (const float*)d_in[10];
  const float* a1  = (const float*)d_in[11];
  const float* ab1 = (const float*)d_in[12];
  const float* a2  = (const float*)d_in[13];
  const float* ab2 = (const float*)d_in[14];
  const float* a3  = (const float*)d_in[15];
  // d_in[16] att3_b: constant shift inside softmax -> no effect on output

  _Float16* wf = (_Float16*)d_ws;  // 48 KB of f16 weights
  prep_weights<<<32, 256, 0, stream>>>(w1, w2, a1, a2, wf);
  uvagg_fused<<<4096, 64, 0, stream>>>(nodes, huv, hr, v2e, u2e, r2e,
                                       b1, b2, ab1, ab2, a3, wf,
                                       (float*)d_out);
}

// Round 14
// 144.752 us; speedup vs baseline: 1.3711x; 1.0753x over previous
//
#include <hip/hip_runtime.h>

// UV_Aggregator fused, 2 b's per wave: grid 2048 x 64, MFMA f16 16x16x32.
// Each wave runs TWO independent b-chains (shared weight fragments, disjoint
// LDS tiles T[0]/T[1]) so gather/LDS latencies of one chain hide under the
// other. Strict phase separation (read->regs, barrier, write), no inline asm.
// __launch_bounds__(64,2): (64,4) caused a 77MB/dispatch spill storm (R10).

#define LNB 50

typedef _Float16 f16x8 __attribute__((ext_vector_type(8)));
typedef float    f32x4 __attribute__((ext_vector_type(4)));

// byte offset into a [64][64] f16 tile (128 B rows), XOR swizzle (T2-style)
__device__ __forceinline__ int swz(int r, int bytecol) {
  return (r * 128 + bytecol) ^ ((r & 7) << 4);
}

// load 8 consecutive fp32, round-to-nearest-even to f16
__device__ __forceinline__ f16x8 cvt8(const float* __restrict__ p) {
  const float4 lo = *(const float4*)p;
  const float4 hi = *(const float4*)(p + 4);
  f16x8 a;
  a[0] = (_Float16)lo.x; a[1] = (_Float16)lo.y;
  a[2] = (_Float16)lo.z; a[3] = (_Float16)lo.w;
  a[4] = (_Float16)hi.x; a[5] = (_Float16)hi.y;
  a[6] = (_Float16)hi.z; a[7] = (_Float16)hi.w;
  return a;
}

// fp32 weights -> f16 in workspace (re-run every call; ws re-poisoned each time)
__global__ void prep_weights(const float* __restrict__ w1, const float* __restrict__ w2,
                             const float* __restrict__ a1, const float* __restrict__ a2,
                             _Float16* __restrict__ wf) {
  int i = blockIdx.x * 256 + threadIdx.x;
  if (i < 8192) wf[i]         = (_Float16)w1[i];   // w_r1_w (64x128)
  if (i < 4096) wf[8192 + i]  = (_Float16)w2[i];   // w_r2_w (64x64)
  if (i < 8192) wf[12288 + i] = (_Float16)a1[i];   // att1_w (64x128)
  if (i < 4096) wf[20480 + i] = (_Float16)a2[i];   // att2_w (64x64)
}

__global__ __launch_bounds__(64, 2) void uvagg_fused2(
    const int* __restrict__ nodes,
    const int* __restrict__ hist_uv,
    const int* __restrict__ hist_r,
    const float* __restrict__ v2e,
    const float* __restrict__ u2e,
    const float* __restrict__ r2e,
    const float* __restrict__ b1,
    const float* __restrict__ b2,
    const float* __restrict__ ab1,
    const float* __restrict__ ab2,
    const float* __restrict__ a3w,
    const _Float16* __restrict__ wf,
    float* __restrict__ out) {
  __shared__ _Float16 T[2][64 * 64];   // 16 KB: H -> O -> P per b, phase-separated
  __shared__ float scb[2][64];
  __shared__ float wtb[2][64];
  const int lane = threadIdx.x;
  const int lr = lane & 15;
  const int kq = lane >> 4;
  const int b0 = blockIdx.x * 2;

  const _Float16* w1f = wf;
  const _Float16* w2f = wf + 8192;
  const _Float16* a1f = wf + 12288;
  const _Float16* a2f = wf + 20480;

  // ---- Phase 1: H = relu([e_uv;e_r] @ W1^T + b1) for both b  [T: WRITE] --
  {
    f16x8 Bf[4][4];   // shared by both b-chains
#pragma unroll
    for (int kt = 0; kt < 4; ++kt)
#pragma unroll
      for (int nt = 0; nt < 4; ++nt)
        Bf[kt][nt] = *(const f16x8*)(w1f + (nt * 16 + lr) * 128 + kt * 32 + kq * 8);

    float bias1[4];
#pragma unroll
    for (int nt = 0; nt < 4; ++nt) bias1[nt] = b1[nt * 16 + lr];

#pragma unroll
    for (int q = 0; q < 2; ++q) {
      char* Tq = (char*)T[q];
#pragma unroll
      for (int m = 0; m < 4; ++m) {
        // pad rows (50..63) clamp to row 49: finite garbage, masked later
        const int rr = (b0 + q) * LNB + (m * 16 + lr < LNB ? m * 16 + lr : LNB - 1);
        const int iu = hist_uv[rr];
        const int ir = hist_r[rr];
        const float* pu = v2e + (size_t)iu * 64;
        const float* pr = r2e + (size_t)ir * 64;   // R=5 -> cache-resident
        f16x8 A[4];
        A[0] = cvt8(pu + kq * 8);
        A[1] = cvt8(pu + 32 + kq * 8);
        A[2] = cvt8(pr + kq * 8);
        A[3] = cvt8(pr + 32 + kq * 8);
#pragma unroll
        for (int nt = 0; nt < 4; ++nt) {
          f32x4 acc = {0.f, 0.f, 0.f, 0.f};
#pragma unroll
          for (int kt = 0; kt < 4; ++kt)
            acc = __builtin_amdgcn_mfma_f32_16x16x32_f16(A[kt], Bf[kt][nt], acc, 0, 0, 0);
          const int c = nt * 16 + lr;
#pragma unroll
          for (int j = 0; j < 4; ++j) {
            const int row = m * 16 + kq * 4 + j;
            const float v = fmaxf(acc[j] + bias1[nt], 0.f);
            *(_Float16*)(Tq + swz(row, 2 * c)) = (_Float16)v;
          }
        }
      }
    }
  }
  __syncthreads();

  // ---- Phase 2: H A-fragments -> registers (both b)  [T: READ] -----------
  f16x8 HA0[2][4], HA1[2][4];
#pragma unroll
  for (int q = 0; q < 2; ++q) {
    const char* Tq = (const char*)T[q];
#pragma unroll
    for (int m = 0; m < 4; ++m) {
      const int r = m * 16 + lr;
      HA0[q][m] = *(const f16x8*)(Tq + swz(r, 2 * (kq * 8)));
      HA1[q][m] = *(const f16x8*)(Tq + swz(r, 2 * (32 + kq * 8)));
    }
  }
  __syncthreads();

  // ---- Phase 3: O = relu(H @ W2^T + b2) from regs  [T: WRITE] ------------
  {
    f16x8 Bf[2][4];
#pragma unroll
    for (int kt = 0; kt < 2; ++kt)
#pragma unroll
      for (int nt = 0; nt < 4; ++nt)
        Bf[kt][nt] = *(const f16x8*)(w2f + (nt * 16 + lr) * 64 + kt * 32 + kq * 8);

    float bias2[4];
#pragma unroll
    for (int nt = 0; nt < 4; ++nt) bias2[nt] = b2[nt * 16 + lr];

#pragma unroll
    for (int q = 0; q < 2; ++q) {
      char* Tq = (char*)T[q];
#pragma unroll
      for (int m = 0; m < 4; ++m) {
#pragma unroll
        for (int nt = 0; nt < 4; ++nt) {
          f32x4 acc = {0.f, 0.f, 0.f, 0.f};
          acc = __builtin_amdgcn_mfma_f32_16x16x32_f16(HA0[q][m], Bf[0][nt], acc, 0, 0, 0);
          acc = __builtin_amdgcn_mfma_f32_16x16x32_f16(HA1[q][m], Bf[1][nt], acc, 0, 0, 0);
          const int c = nt * 16 + lr;
#pragma unroll
          for (int j = 0; j < 4; ++j) {
            const int row = m * 16 + kq * 4 + j;
            const float v = fmaxf(acc[j] + bias2[nt], 0.f);
            *(_Float16*)(Tq + swz(row, 2 * c)) = (_Float16)v;
          }
        }
      }
    }
  }
  __syncthreads();

  // ---- Phase 4: O A-fragments -> registers (live to end)  [T: READ] ------
  f16x8 OA0[2][4], OA1[2][4];
#pragma unroll
  for (int q = 0; q < 2; ++q) {
    const char* Tq = (const char*)T[q];
#pragma unroll
    for (int m = 0; m < 4; ++m) {
      const int r = m * 16 + lr;
      OA0[q][m] = *(const f16x8*)(Tq + swz(r, 2 * (kq * 8)));
      OA1[q][m] = *(const f16x8*)(Tq + swz(r, 2 * (32 + kq * 8)));
    }
  }
  __syncthreads();

  // ---- Phase 5: P = relu([O ; uv_rep] @ A1^T + ab1)  [T: WRITE] ----------
  {
    // uv_rep contribution is row-constant per b: compute once per (q,nt)
    f32x4 acc_u[2][4];
    {
      f16x8 Bu[2][4];   // shared by both b-chains
#pragma unroll
      for (int kt = 0; kt < 2; ++kt)
#pragma unroll
        for (int nt = 0; nt < 4; ++nt)
          Bu[kt][nt] = *(const f16x8*)(a1f + (nt * 16 + lr) * 128 + (kt + 2) * 32 + kq * 8);
#pragma unroll
      for (int q = 0; q < 2; ++q) {
        const int node = nodes[b0 + q];
        const f16x8 U2 = cvt8(u2e + (size_t)node * 64 + kq * 8);
        const f16x8 U3 = cvt8(u2e + (size_t)node * 64 + 32 + kq * 8);
#pragma unroll
        for (int nt = 0; nt < 4; ++nt) {
          f32x4 acc = {0.f, 0.f, 0.f, 0.f};
          acc = __builtin_amdgcn_mfma_f32_16x16x32_f16(U2, Bu[0][nt], acc, 0, 0, 0);
          acc = __builtin_amdgcn_mfma_f32_16x16x32_f16(U3, Bu[1][nt], acc, 0, 0, 0);
          acc_u[q][nt] = acc;
        }
      }
    }

    f16x8 Bf[2][4];
#pragma unroll
    for (int kt = 0; kt < 2; ++kt)
#pragma unroll
      for (int nt = 0; nt < 4; ++nt)
        Bf[kt][nt] = *(const f16x8*)(a1f + (nt * 16 + lr) * 128 + kt * 32 + kq * 8);

    float biasa1[4];
#pragma unroll
    for (int nt = 0; nt < 4; ++nt) biasa1[nt] = ab1[nt * 16 + lr];

#pragma unroll
    for (int q = 0; q < 2; ++q) {
      char* Tq = (char*)T[q];
#pragma unroll
      for (int m = 0; m < 4; ++m) {
#pragma unroll
        for (int nt = 0; nt < 4; ++nt) {
          f32x4 acc = acc_u[q][nt];
          acc = __builtin_amdgcn_mfma_f32_16x16x32_f16(OA0[q][m], Bf[0][nt], acc, 0, 0, 0);
          acc = __builtin_amdgcn_mfma_f32_16x16x32_f16(OA1[q][m], Bf[1][nt], acc, 0, 0, 0);
          const int c = nt * 16 + lr;
#pragma unroll
          for (int j = 0; j < 4; ++j) {
            const int row = m * 16 + kq * 4 + j;
            const float v = fmaxf(acc[j] + biasa1[nt], 0.f);
            *(_Float16*)(Tq + swz(row, 2 * c)) = (_Float16)v;
          }
        }
      }
    }
  }
  __syncthreads();

  // ---- Phase 6: s = relu(P @ A2^T + ab2) . a3  [T: READ only] ------------
  {
    f16x8 Bf[2][4];
#pragma unroll
    for (int kt = 0; kt < 2; ++kt)
#pragma unroll
      for (int nt = 0; nt < 4; ++nt)
        Bf[kt][nt] = *(const f16x8*)(a2f + (nt * 16 + lr) * 64 + kt * 32 + kq * 8);

    float biasa2[4], a3c[4];
#pragma unroll
    for (int nt = 0; nt < 4; ++nt) {
      biasa2[nt] = ab2[nt * 16 + lr];
      a3c[nt] = a3w[nt * 16 + lr];
    }

#pragma unroll
    for (int m = 0; m < 4; ++m) {
      const int r = m * 16 + lr;
      f16x8 A0q[2], A1q[2];
#pragma unroll
      for (int q = 0; q < 2; ++q) {
        const char* Tq = (const char*)T[q];
        A0q[q] = *(const f16x8*)(Tq + swz(r, 2 * (kq * 8)));
        A1q[q] = *(const f16x8*)(Tq + swz(r, 2 * (32 + kq * 8)));
      }
      float part[2][4] = {{0.f,0.f,0.f,0.f},{0.f,0.f,0.f,0.f}};
#pragma unroll
      for (int nt = 0; nt < 4; ++nt) {
#pragma unroll
        for (int q = 0; q < 2; ++q) {
          f32x4 acc = {0.f, 0.f, 0.f, 0.f};
          acc = __builtin_amdgcn_mfma_f32_16x16x32_f16(A0q[q], Bf[0][nt], acc, 0, 0, 0);
          acc = __builtin_amdgcn_mfma_f32_16x16x32_f16(A1q[q], Bf[1][nt], acc, 0, 0, 0);
#pragma unroll
          for (int j = 0; j < 4; ++j) {
            const float v = fmaxf(acc[j] + biasa2[nt], 0.f);
            part[q][j] += v * a3c[nt];
          }
        }
      }
#pragma unroll
      for (int mask = 1; mask < 16; mask <<= 1)
#pragma unroll
        for (int q = 0; q < 2; ++q)
#pragma unroll
          for (int j = 0; j < 4; ++j) part[q][j] += __shfl_xor(part[q][j], mask);
      if (lr == 0) {
#pragma unroll
        for (int q = 0; q < 2; ++q)
#pragma unroll
          for (int j = 0; j < 4; ++j) scb[q][m * 16 + kq * 4 + j] = part[q][j];
      }
    }
  }
  __syncthreads();

  // ---- Phase 7: softmax over neighbors, both b (att3_b shift-invariant) --
  {
    float sv[2], mx[2], e[2], s[2];
#pragma unroll
    for (int q = 0; q < 2; ++q) { sv[q] = (lane < LNB) ? scb[q][lane] : -1e30f; mx[q] = sv[q]; }
#pragma unroll
    for (int mask = 1; mask < 64; mask <<= 1)
#pragma unroll
      for (int q = 0; q < 2; ++q) mx[q] = fmaxf(mx[q], __shfl_xor(mx[q], mask));
#pragma unroll
    for (int q = 0; q < 2; ++q) { e[q] = __expf(sv[q] - mx[q]); s[q] = e[q]; }
#pragma unroll
    for (int mask = 1; mask < 64; mask <<= 1)
#pragma unroll
      for (int q = 0; q < 2; ++q) s[q] += __shfl_xor(s[q], mask);
#pragma unroll
    for (int q = 0; q < 2; ++q) wtb[q][lane] = (lane < LNB) ? (e[q] / s[q]) : 0.f;
  }
  __syncthreads();

  // ---- Phase 8: weighted sums from O register fragments ------------------
  {
    float wrow[2][4];
#pragma unroll
    for (int q = 0; q < 2; ++q)
#pragma unroll
      for (int m = 0; m < 4; ++m) wrow[q][m] = wtb[q][m * 16 + lr];

    float p0[2][8] = {{0,0,0,0,0,0,0,0},{0,0,0,0,0,0,0,0}};
    float p1[2][8] = {{0,0,0,0,0,0,0,0},{0,0,0,0,0,0,0,0}};
#pragma unroll
    for (int q = 0; q < 2; ++q)
#pragma unroll
      for (int m = 0; m < 4; ++m)
#pragma unroll
        for (int i = 0; i < 8; ++i) {
          p0[q][i] += wrow[q][m] * (float)OA0[q][m][i];
          p1[q][i] += wrow[q][m] * (float)OA1[q][m][i];
        }
    // reduce over the 16 rows (lr) within each kq group
#pragma unroll
    for (int mask = 1; mask < 16; mask <<= 1)
#pragma unroll
      for (int q = 0; q < 2; ++q)
#pragma unroll
        for (int i = 0; i < 8; ++i) {
          p0[q][i] += __shfl_xor(p0[q][i], mask);
          p1[q][i] += __shfl_xor(p1[q][i], mask);
        }
    if (lr == 0) {
#pragma unroll
      for (int q = 0; q < 2; ++q)
#pragma unroll
        for (int i = 0; i < 8; ++i) {
          scb[q][kq * 8 + i] = p0[q][i];
          scb[q][32 + kq * 8 + i] = p1[q][i];
        }
    }
  }
  __syncthreads();
#pragma unroll
  for (int q = 0; q < 2; ++q)
    out[(size_t)(b0 + q) * 64 + lane] = scb[q][lane];
}

extern "C" void kernel_launch(void* const* d_in, const int* in_sizes, int n_in,
                              void* d_out, int out_size, void* d_ws, size_t ws_size,
                              hipStream_t stream) {
  (void)in_sizes; (void)n_in; (void)out_size; (void)ws_size;
  const int* nodes = (const int*)d_in[0];
  const int* huv   = (const int*)d_in[1];
  const int* hr    = (const int*)d_in[2];
  // d_in[3] history_uvt: unused by reference
  const float* v2e = (const float*)d_in[4];
  const float* u2e = (const float*)d_in[5];
  const float* r2e = (const float*)d_in[6];
  const float* w1  = (const float*)d_in[7];
  const float* b1  = (const float*)d_in[8];
  const float* w2  = (const float*)d_in[9];
  const float* b2  = (const float*)d_in[10];
  const float* a1  = (const float*)d_in[11];
  const float* ab1 = (const float*)d_in[12];
  const float* a2  = (const float*)d_in[13];
  const float* ab2 = (const float*)d_in[14];
  const float* a3  = (const float*)d_in[15];
  // d_in[16] att3_b: constant shift inside softmax -> no effect on output

  _Float16* wf = (_Float16*)d_ws;  // 48 KB of f16 weights
  prep_weights<<<32, 256, 0, stream>>>(w1, w2, a1, a2, wf);
  uvagg_fused2<<<2048, 64, 0, stream>>>(nodes, huv, hr, v2e, u2e, r2e,
                                        b1, b2, ab1, ab2, a3, wf,
                                        (float*)d_out);
}